// Round 6
// baseline (168.632 us; speedup 1.0000x reference)
//
#include <hip/hip_runtime.h>
#include <hip/hip_bf16.h>
#include <stdint.h>

typedef __hip_bfloat16 bf16;
typedef __attribute__((ext_vector_type(8))) short bf16x8;
typedef __attribute__((ext_vector_type(4))) float f32x4;
typedef __attribute__((ext_vector_type(8))) unsigned short u16x8;
typedef __attribute__((ext_vector_type(4))) unsigned short u16x4;

#define SLEN 2048
#define ED   1024
#define NB   4
#define AS1 __attribute__((address_space(1)))
#define AS3 __attribute__((address_space(3)))

static __device__ __forceinline__ unsigned short f2bf(float f) {
    return __builtin_bit_cast(unsigned short, __float2bfloat16(f));
}

// ============================================================================
// 256x128 / BK=64 / 512-thread GEMM core. 8 waves (4M x 2N), wave tile 64x64.
// LDS 96KB: 2 bufs x {A planes [kh][256][32], B planes [kh][128][32]} ->
// 1 block/CU, 8 waves. Per K-tile: 2 phases (kh). Per phase:
//   {8 ds_read_b128; STAGE (A-kh',B-kh') of tile T+1 (3 loads/thr);
//    vmcnt(3); barrier; lgkmcnt(0); setprio(1); 16 MFMA; setprio(0); barrier}
// Counted-wait proof (per-wave queue, loads/unit = [Ak0:2,Bk0:1,Ak1:2,Bk1:1]):
//   entering tile T: outstanding = [T.Ak1(2), T.Bk1(1)] = 3.
//   p0: stage T1.Ak0,T1.Bk0 -> 6; vmcnt(3) retires T.Ak1,T.Bk1 (read at p1).
//   p1: stage T1.Ak1,T1.Bk1 -> 6; vmcnt(3) retires T1.Ak0,T1.Bk0 (read next p0).
//   All waves vmcnt before the barrier -> after barrier the plane is complete
//   for every wave's portion. Final tile: vmcnt(0) (queue <=3).
// Overwrite safety: plane written at tile T was last ds_read at tile T-1,
// drained by each reader's lgkmcnt(0) two barriers earlier.
// Swizzle (both sides, involution): 16B chunk c of a 64B row at c^((row>>1)&3)
// -> 2-way bank aliasing (free, m136); measured 0 conflicts in R3/R4.
// ============================================================================
__device__ __forceinline__ void gemm_core(
    const char* __restrict__ aT, int lda,   // A: 256 rows, k contiguous
    const char* __restrict__ bT, int ldb,   // B: 128 rows (n-major), k contig
    int nkt, char* sm, int tid, f32x4 (&acc)[4][4])
{
    const int lane = tid & 63, wave = tid >> 6;
    const int wm = wave >> 1, wn = wave & 1;
    const int fr = lane & 15, kc = lane >> 4;

    // stage planes (A-kh, B-kh) of K-tile Tn into buffer Tn&1
    auto STAGE = [&](int kh, int Tn) {
        char* buf = sm + (Tn & 1) * 49152;
        // A plane: 16KB, 2 loads/thread
#pragma unroll
        for (int j = 0; j < 2; ++j) {
            int rid = j * 512 + tid;
            int row = rid >> 2, c = rid & 3;
            const char* src = aT + (size_t)row * lda + Tn * 128 + kh * 64
                            + ((c ^ ((row >> 1) & 3)) * 16);
            __builtin_amdgcn_global_load_lds(
                (const AS1 uint32_t*)src,
                (AS3 uint32_t*)(buf + kh * 16384 + (j * 512 + wave * 64) * 16),
                16, 0, 0);
        }
        // B plane: 8KB, 1 load/thread
        {
            int row = tid >> 2, c = tid & 3;
            const char* src = bT + (size_t)row * ldb + Tn * 128 + kh * 64
                            + ((c ^ ((row >> 1) & 3)) * 16);
            __builtin_amdgcn_global_load_lds(
                (const AS1 uint32_t*)src,
                (AS3 uint32_t*)(buf + 32768 + kh * 8192 + (wave * 64) * 16),
                16, 0, 0);
        }
    };

    // prologue: stage tile 0 fully (6 loads); vmcnt(3) -> Ak0,Bk0 landed
    STAGE(0, 0); STAGE(1, 0);
    asm volatile("s_waitcnt vmcnt(3)" ::: "memory");
    __builtin_amdgcn_sched_barrier(0);
    __builtin_amdgcn_s_barrier();

    for (int T = 0; T < nkt; ++T) {
        const bool pre = (T + 1 < nkt);
        const char* buf = sm + (T & 1) * 49152;
#pragma unroll
        for (int kh = 0; kh < 2; ++kh) {
            bf16x8 a[4], b[4];
#pragma unroll
            for (int i = 0; i < 4; ++i) {
                int row = wm * 64 + i * 16 + fr;
                a[i] = *(const bf16x8*)(buf + kh * 16384 + row * 64
                                        + ((kc ^ ((row >> 1) & 3)) * 16));
            }
#pragma unroll
            for (int i = 0; i < 4; ++i) {
                int row = wn * 64 + i * 16 + fr;
                b[i] = *(const bf16x8*)(buf + 32768 + kh * 8192 + row * 64
                                        + ((kc ^ ((row >> 1) & 3)) * 16));
            }
            if (pre) {
                STAGE(kh, T + 1);
                asm volatile("s_waitcnt vmcnt(3)" ::: "memory");
            } else {
                asm volatile("s_waitcnt vmcnt(0)" ::: "memory");
            }
            __builtin_amdgcn_sched_barrier(0);
            __builtin_amdgcn_s_barrier();
            asm volatile("s_waitcnt lgkmcnt(0)" ::: "memory");
            __builtin_amdgcn_sched_barrier(0);
            __builtin_amdgcn_s_setprio(1);
#pragma unroll
            for (int i = 0; i < 4; ++i)
#pragma unroll
                for (int n = 0; n < 4; ++n)
                    acc[i][n] = __builtin_amdgcn_mfma_f32_16x16x32_bf16(
                        a[i], b[n], acc[i][n], 0, 0, 0);
            __builtin_amdgcn_s_setprio(0);
            __builtin_amdgcn_s_barrier();
        }
    }
}

// ---------------- convert fp32 -> bf16 (x and the 3 weights) ----------------
__global__ __launch_bounds__(256) void convert_to_bf16(
    const float* __restrict__ x, const float* __restrict__ wq,
    const float* __restrict__ wk, const float* __restrict__ wv,
    bf16* __restrict__ xb, bf16* __restrict__ wqb,
    bf16* __restrict__ wkb, bf16* __restrict__ wvb)
{
    long g = (long)blockIdx.x * 256 + threadIdx.x;   // each thread: 8 elements
    const float* src; bf16* dst; long o;
    if (g < 1048576) { src = x; dst = xb; o = g * 8; }
    else {
        long g2 = g - 1048576;
        int w = (int)(g2 >> 17);
        o = (g2 & 131071) * 8;
        src = (w == 0) ? wq : (w == 1) ? wk : wv;
        dst = (w == 0) ? wqb : (w == 1) ? wkb : wvb;
    }
    float4 v0 = *(const float4*)(src + o);
    float4 v1 = *(const float4*)(src + o + 4);
    u16x8 r;
    r[0] = f2bf(v0.x); r[1] = f2bf(v0.y); r[2] = f2bf(v0.z); r[3] = f2bf(v0.w);
    r[4] = f2bf(v1.x); r[5] = f2bf(v1.y); r[6] = f2bf(v1.z); r[7] = f2bf(v1.w);
    *(u16x8*)(dst + o) = r;
}

// ---------------- fused QKV: [8192,3072] = xb @ [wq;wk;wv]^T ----------------
// 768 blocks (256x128 tiles) = 3 exact rounds at 1 block/CU.
// XCD swizzle: each XCD owns 4 tm values (A slice = 2 MB, L2-resident).
__global__ __launch_bounds__(512, 2) void qkv_gemm(
    const bf16* __restrict__ xb, const bf16* __restrict__ wqb,
    const bf16* __restrict__ wkb, const bf16* __restrict__ wvb,
    bf16* __restrict__ Qb, bf16* __restrict__ Kb, bf16* __restrict__ Vt)
{
    extern __shared__ char smem[];
    int bid = blockIdx.x, tid = threadIdx.x;
    int xcd = bid & 7, i = bid >> 3;            // i in 0..95
    int tm = (xcd << 2) | (i & 3);              // 0..31
    int tn = i >> 2;                            // 0..23
    const bf16* W = (tn < 8) ? wqb : (tn < 16) ? wkb : wvb;
    int tnl = tn & 7;
    f32x4 acc[4][4] = {};
    gemm_core((const char*)(xb + (size_t)tm * 256 * ED), ED * 2,
              (const char*)(W + (size_t)tnl * 128 * ED), ED * 2,
              16, smem, tid, acc);

    int lane = tid & 63, wave = tid >> 6, wm = wave >> 1, wn = wave & 1;
    int rl = (lane >> 4) * 4, cl = lane & 15;
    if (tn < 16) {
        bf16* C = (tn < 8) ? Qb : Kb;
#pragma unroll
        for (int mf = 0; mf < 4; ++mf)
#pragma unroll
            for (int j = 0; j < 4; ++j) {
                int r = tm * 256 + wm * 64 + mf * 16 + rl + j;
#pragma unroll
                for (int nf = 0; nf < 4; ++nf) {
                    int c = tnl * 128 + wn * 64 + nf * 16 + cl;
                    C[(size_t)r * ED + c] = __float2bfloat16(acc[mf][nf][j]);
                }
            }
    } else {
#pragma unroll
        for (int mf = 0; mf < 4; ++mf)
#pragma unroll
            for (int j = 0; j < 4; ++j) {
                int r = tm * 256 + wm * 64 + mf * 16 + rl + j;
                int bb = r >> 11, s = r & 2047;
#pragma unroll
                for (int nf = 0; nf < 4; ++nf) {
                    int d = tnl * 128 + wn * 64 + nf * 16 + cl;
                    Vt[(((size_t)bb << 10) + d) * SLEN + s] = __float2bfloat16(acc[mf][nf][j]);
                }
            }
    }
}

// ---------------- scores = Q @ K^T / 32, causal 256x128 tiles ---------------
// keep tile (ti,tj) iff tj <= 2*ti+1 -> 72 tiles/batch, grid (72, NB).
__global__ __launch_bounds__(512, 2) void qk_gemm(
    const bf16* __restrict__ Qb, const bf16* __restrict__ Kb, float* __restrict__ Sc)
{
    extern __shared__ char smem[];
    int bx = blockIdx.x, b = blockIdx.y, tid = threadIdx.x;
    int t = (bx & 7) * 9 + (bx >> 3);            // XCD swizzle, 72 = 8*9, bijective
    int ti = 0;
    while ((ti + 1) * (ti + 2) <= t) ++ti;       // prefix(ti) = ti*(ti+1)
    int tj = t - ti * (ti + 1);
    f32x4 acc[4][4] = {};
    gemm_core((const char*)(Qb + ((size_t)b * SLEN + ti * 256) * ED), ED * 2,
              (const char*)(Kb + ((size_t)b * SLEN + tj * 128) * ED), ED * 2,
              16, smem, tid, acc);

    float* Sb = Sc + (size_t)b * SLEN * SLEN;
    int lane = tid & 63, wave = tid >> 6, wm = wave >> 1, wn = wave & 1;
    int rl = (lane >> 4) * 4, cl = lane & 15;
#pragma unroll
    for (int mf = 0; mf < 4; ++mf)
#pragma unroll
        for (int j = 0; j < 4; ++j) {
            int r = ti * 256 + wm * 64 + mf * 16 + rl + j;
#pragma unroll
            for (int nf = 0; nf < 4; ++nf) {
                int c = tj * 128 + wn * 64 + nf * 16 + cl;
                Sb[(size_t)r * SLEN + c] = acc[mf][nf][j] * 0.03125f;
            }
        }
}

// ---------------- causal row softmax; writes P (bf16) over the score row ----
__global__ __launch_bounds__(256) void softmax_rows(float* __restrict__ Sc)
{
    int q = blockIdx.x, b = blockIdx.y, tid = threadIdx.x;
    float* row = Sc + ((size_t)b * SLEN + q) * SLEN;
    int lane = tid & 63, wave = tid >> 6;
    __shared__ float red[4];

    float vals[8];
    float lmax = -3.0e38f;
#pragma unroll
    for (int r = 0; r < 2; ++r) {
        int i4 = tid + r * 256;
        if (i4 * 4 <= q) {                       // skip fully-masked chunks
            float4 v = *(const float4*)(row + i4 * 4);
            vals[r * 4 + 0] = v.x; vals[r * 4 + 1] = v.y;
            vals[r * 4 + 2] = v.z; vals[r * 4 + 3] = v.w;
#pragma unroll
            for (int e = 0; e < 4; ++e) {
                int k = i4 * 4 + e;
                if (k <= q) lmax = fmaxf(lmax, vals[r * 4 + e]);
            }
        }
    }
#pragma unroll
    for (int o = 32; o > 0; o >>= 1) lmax = fmaxf(lmax, __shfl_xor(lmax, o));
    if (lane == 0) red[wave] = lmax;
    __syncthreads();
    float m = fmaxf(fmaxf(red[0], red[1]), fmaxf(red[2], red[3]));
    __syncthreads();
    float lsum = 0.f;
#pragma unroll
    for (int r = 0; r < 2; ++r) {
        int i4 = tid + r * 256;
        if (i4 * 4 <= q)
#pragma unroll
            for (int e = 0; e < 4; ++e) {
                int k = i4 * 4 + e;
                if (k <= q) lsum += __expf(vals[r * 4 + e] - m);
            }
    }
#pragma unroll
    for (int o = 32; o > 0; o >>= 1) lsum += __shfl_xor(lsum, o);
    if (lane == 0) red[wave] = lsum;
    __syncthreads();
    float inv = 1.0f / (red[0] + red[1] + red[2] + red[3]);
    unsigned short* prow = (unsigned short*)row;
#pragma unroll
    for (int r = 0; r < 2; ++r) {
        int i4 = tid + r * 256;
        u16x4 o4;
#pragma unroll
        for (int e = 0; e < 4; ++e) {
            int k = i4 * 4 + e;
            float p = (k <= q) ? __expf(vals[r * 4 + e] - m) * inv : 0.0f;
            o4[e] = f2bf(p);
        }
        *(u16x4*)(prow + i4 * 4) = o4;           // full store: pv reads zeros
    }
}

// ---------------- O = P @ V (P bf16 ld 4096 elems; Vt [b][d][s]) ------------
// 256x128 tiles: grid 8 mq x 8 nd x 4 b = 256 blocks (exact fill).
__global__ __launch_bounds__(512, 2) void pv_gemm(
    const bf16* __restrict__ P, const bf16* __restrict__ Vt, float* __restrict__ O)
{
    extern __shared__ char smem[];
    int mq = 7 - blockIdx.x, nd = blockIdx.y, b = blockIdx.z, tid = threadIdx.x;
    f32x4 acc[4][4] = {};
    int nkt = (mq + 1) * 4;                      // causal: k < (mq+1)*256
    gemm_core((const char*)P + ((size_t)b * SLEN + mq * 256) * 8192, 8192,
              (const char*)(Vt + ((size_t)b * ED + nd * 128) * SLEN), SLEN * 2,
              nkt, smem, tid, acc);

    int lane = tid & 63, wave = tid >> 6, wm = wave >> 1, wn = wave & 1;
    int rl = (lane >> 4) * 4, cl = lane & 15;
    float* Ob = O + (size_t)b * SLEN * ED;
#pragma unroll
    for (int mf = 0; mf < 4; ++mf)
#pragma unroll
        for (int j = 0; j < 4; ++j) {
            int r = mq * 256 + wm * 64 + mf * 16 + rl + j;
#pragma unroll
            for (int nf = 0; nf < 4; ++nf) {
                int c = nd * 128 + wn * 64 + nf * 16 + cl;
                Ob[(size_t)r * ED + c] = acc[mf][nf][j];
            }
        }
}

extern "C" void kernel_launch(void* const* d_in, const int* in_sizes, int n_in,
                              void* d_out, int out_size, void* d_ws, size_t ws_size,
                              hipStream_t stream)
{
    const float* x  = (const float*)d_in[0];
    const float* wq = (const float*)d_in[1];
    const float* wk = (const float*)d_in[2];
    const float* wv = (const float*)d_in[3];
    float* out = (float*)d_out;

    char* ws = (char*)d_ws;
    bf16* xb  = (bf16*)(ws);                       // 16 MB
    bf16* wqb = (bf16*)(ws + 16777216);            // 2 MB
    bf16* wkb = (bf16*)(ws + 18874368);            // 2 MB
    bf16* wvb = (bf16*)(ws + 20971520);            // 2 MB
    bf16* Qb  = (bf16*)(ws + 23068672);            // 16 MB
    bf16* Kb  = (bf16*)(ws + 39845888);            // 16 MB
    bf16* Vt  = (bf16*)(ws + 56623104);            // 16 MB
    float* Sc = (float*)(ws + 73400320);           // 64 MB (P bf16 aliases this)

    (void)hipFuncSetAttribute((const void*)qkv_gemm,
            hipFuncAttributeMaxDynamicSharedMemorySize, 98304);
    (void)hipFuncSetAttribute((const void*)qk_gemm,
            hipFuncAttributeMaxDynamicSharedMemorySize, 98304);
    (void)hipFuncSetAttribute((const void*)pv_gemm,
            hipFuncAttributeMaxDynamicSharedMemorySize, 98304);

    convert_to_bf16<<<5632, 256, 0, stream>>>(x, wq, wk, wv, xb, wqb, wkb, wvb);
    qkv_gemm<<<768, 512, 98304, stream>>>(xb, wqb, wkb, wvb, Qb, Kb, Vt);
    qk_gemm<<<dim3(72, NB), 512, 98304, stream>>>(Qb, Kb, Sc);
    softmax_rows<<<dim3(SLEN, NB), 256, 0, stream>>>(Sc);
    pv_gemm<<<dim3(8, 8, NB), 512, 98304, stream>>>((const bf16*)Sc, Vt, out);
}

// Round 7
// 155.070 us; speedup vs baseline: 1.0875x; 1.0875x over previous
//
#include <hip/hip_runtime.h>
#include <hip/hip_bf16.h>
#include <stdint.h>

typedef __hip_bfloat16 bf16;
typedef __attribute__((ext_vector_type(8))) short bf16x8;
typedef __attribute__((ext_vector_type(4))) float f32x4;
typedef __attribute__((ext_vector_type(8))) unsigned short u16x8;
typedef __attribute__((ext_vector_type(4))) unsigned short u16x4;

#define SLEN 2048
#define ED   1024
#define NB   4
#define AS1 __attribute__((address_space(1)))
#define AS3 __attribute__((address_space(3)))
#define SB0() __builtin_amdgcn_sched_barrier(0)

static __device__ __forceinline__ unsigned short f2bf(float f) {
    return __builtin_bit_cast(unsigned short, __float2bfloat16(f));
}

// ============================================================================
// 256x128 / BK=64 / 512-thread GEMM core with REGISTER FRAGMENT PIPELINING.
// 8 waves (4M x 2N), wave tile 64x64. LDS 96KB (2 bufs x 2 kh-planes), 1 blk/CU.
// Plane p = (T=p>>1, kh=p&1). Phase p:
//   { RD plane p -> bank[p&1] (8 ds_read_b128); STAGE plane p+2 (3 gload_lds);
//     lgkmcnt(8) [waits bank[(p-1)&1], DS in-order]; MFMA bank[(p-1)&1];
//     vmcnt(3) [retires plane p+1; counted, 0 only in last tile]; s_barrier }
// LDS reads of phase p+1 overlap MFMAs of phase p (separate pipes); ONE
// barrier/phase. Invariants (same cadence as R6, proof re-checked):
//  - RD(p) safe: plane p's loads retired by phase p-1's vmcnt(3) + barrier.
//  - lgkm(8): 16 DS ops outstanding max; oldest 8 = previous bank; DS FIFO.
//  - overwrite slot (p+2)&3 = (p-2)&3: last reads (phase p-2) drained by
//    phase p-1's lgkm(8) before its barrier, which precedes phase p's STAGE.
// Swizzle (both-sides involution): chunk c at c^((row>>1)&3) -> 2-way only
// (free, m136); measured 0 conflicts R3-R6.
// ============================================================================
__device__ __forceinline__ void gemm_core(
    const char* __restrict__ aT, int lda,   // A: 256 rows, k contiguous
    const char* __restrict__ bT, int ldb,   // B: 128 rows (n-major), k contig
    int nkt, char* sm, int tid, f32x4 (&acc)[4][4])
{
    const int lane = tid & 63, wave = tid >> 6;
    const int wm = wave >> 1, wn = wave & 1;
    const int fr = lane & 15, kc = lane >> 4;

    auto STAGE = [&](int kh, int Tn) {
        char* buf = sm + (Tn & 1) * 49152;
#pragma unroll
        for (int j = 0; j < 2; ++j) {
            int rid = j * 512 + tid;
            int row = rid >> 2, c = rid & 3;
            const char* src = aT + (size_t)row * lda + Tn * 128 + kh * 64
                            + ((c ^ ((row >> 1) & 3)) * 16);
            __builtin_amdgcn_global_load_lds(
                (const AS1 uint32_t*)src,
                (AS3 uint32_t*)(buf + kh * 16384 + (j * 512 + wave * 64) * 16),
                16, 0, 0);
        }
        {
            int row = tid >> 2, c = tid & 3;
            const char* src = bT + (size_t)row * ldb + Tn * 128 + kh * 64
                            + ((c ^ ((row >> 1) & 3)) * 16);
            __builtin_amdgcn_global_load_lds(
                (const AS1 uint32_t*)src,
                (AS3 uint32_t*)(buf + 32768 + kh * 8192 + (wave * 64) * 16),
                16, 0, 0);
        }
    };
    auto RD = [&](int T, int kh, bf16x8 (&a)[4], bf16x8 (&b)[4]) {
        const char* buf = sm + (T & 1) * 49152;
#pragma unroll
        for (int i = 0; i < 4; ++i) {
            int row = wm * 64 + i * 16 + fr;
            a[i] = *(const bf16x8*)(buf + kh * 16384 + row * 64
                                    + ((kc ^ ((row >> 1) & 3)) * 16));
        }
#pragma unroll
        for (int i = 0; i < 4; ++i) {
            int row = wn * 64 + i * 16 + fr;
            b[i] = *(const bf16x8*)(buf + 32768 + kh * 8192 + row * 64
                                    + ((kc ^ ((row >> 1) & 3)) * 16));
        }
    };
    auto MM = [&](bf16x8 (&a)[4], bf16x8 (&b)[4]) {
        __builtin_amdgcn_s_setprio(1);
#pragma unroll
        for (int i = 0; i < 4; ++i)
#pragma unroll
            for (int n = 0; n < 4; ++n)
                acc[i][n] = __builtin_amdgcn_mfma_f32_16x16x32_bf16(
                    a[i], b[n], acc[i][n], 0, 0, 0);
        __builtin_amdgcn_s_setprio(0);
    };

    // prologue: stage tile 0 (planes 0,1); vmcnt(3) -> plane 0 landed
    STAGE(0, 0); STAGE(1, 0);
    asm volatile("s_waitcnt vmcnt(3)" ::: "memory");
    SB0();
    __builtin_amdgcn_s_barrier();

    bf16x8 aE[4], bE[4], aO[4], bO[4];
    for (int T = 0; T < nkt; ++T) {
        const bool pre = (T + 1 < nkt);
        // ---- even phase p=2T: read plane 2T, MFMA plane 2T-1 (bank O) ----
        RD(T, 0, aE, bE);
        SB0();
        if (pre) STAGE(0, T + 1);
        SB0();
        if (T > 0) {
            asm volatile("s_waitcnt lgkmcnt(8)" ::: "memory");
            SB0();
            MM(aO, bO);
        }
        if (pre) asm volatile("s_waitcnt vmcnt(3)" ::: "memory");
        else     asm volatile("s_waitcnt vmcnt(0)" ::: "memory");
        SB0();
        __builtin_amdgcn_s_barrier();
        // ---- odd phase p=2T+1: read plane 2T+1, MFMA plane 2T (bank E) ----
        RD(T, 1, aO, bO);
        SB0();
        if (pre) STAGE(1, T + 1);
        SB0();
        asm volatile("s_waitcnt lgkmcnt(8)" ::: "memory");
        SB0();
        MM(aE, bE);
        if (pre) asm volatile("s_waitcnt vmcnt(3)" ::: "memory");
        else     asm volatile("s_waitcnt vmcnt(0)" ::: "memory");
        SB0();
        __builtin_amdgcn_s_barrier();
    }
    // epilogue: last plane (bank O)
    asm volatile("s_waitcnt lgkmcnt(0)" ::: "memory");
    SB0();
    MM(aO, bO);
}

// ---------------- convert fp32 -> bf16 (x and the 3 weights) ----------------
__global__ __launch_bounds__(256) void convert_to_bf16(
    const float* __restrict__ x, const float* __restrict__ wq,
    const float* __restrict__ wk, const float* __restrict__ wv,
    bf16* __restrict__ xb, bf16* __restrict__ wqb,
    bf16* __restrict__ wkb, bf16* __restrict__ wvb)
{
    long g = (long)blockIdx.x * 256 + threadIdx.x;   // each thread: 8 elements
    const float* src; bf16* dst; long o;
    if (g < 1048576) { src = x; dst = xb; o = g * 8; }
    else {
        long g2 = g - 1048576;
        int w = (int)(g2 >> 17);
        o = (g2 & 131071) * 8;
        src = (w == 0) ? wq : (w == 1) ? wk : wv;
        dst = (w == 0) ? wqb : (w == 1) ? wkb : wvb;
    }
    float4 v0 = *(const float4*)(src + o);
    float4 v1 = *(const float4*)(src + o + 4);
    u16x8 r;
    r[0] = f2bf(v0.x); r[1] = f2bf(v0.y); r[2] = f2bf(v0.z); r[3] = f2bf(v0.w);
    r[4] = f2bf(v1.x); r[5] = f2bf(v1.y); r[6] = f2bf(v1.z); r[7] = f2bf(v1.w);
    *(u16x8*)(dst + o) = r;
}

// ---------------- fused QKV: [8192,3072] = xb @ [wq;wk;wv]^T ----------------
// 768 blocks (256x128 tiles) = 3 exact rounds at 1 block/CU.
// XCD swizzle: each XCD owns 4 tm values (A slice = 2 MB, L2-resident).
__global__ __launch_bounds__(512, 2) void qkv_gemm(
    const bf16* __restrict__ xb, const bf16* __restrict__ wqb,
    const bf16* __restrict__ wkb, const bf16* __restrict__ wvb,
    bf16* __restrict__ Qb, bf16* __restrict__ Kb, bf16* __restrict__ Vt)
{
    extern __shared__ char smem[];
    int bid = blockIdx.x, tid = threadIdx.x;
    int xcd = bid & 7, i = bid >> 3;            // i in 0..95
    int tm = (xcd << 2) | (i & 3);              // 0..31
    int tn = i >> 2;                            // 0..23
    const bf16* W = (tn < 8) ? wqb : (tn < 16) ? wkb : wvb;
    int tnl = tn & 7;
    f32x4 acc[4][4] = {};
    gemm_core((const char*)(xb + (size_t)tm * 256 * ED), ED * 2,
              (const char*)(W + (size_t)tnl * 128 * ED), ED * 2,
              16, smem, tid, acc);

    int lane = tid & 63, wave = tid >> 6, wm = wave >> 1, wn = wave & 1;
    int rl = (lane >> 4) * 4, cl = lane & 15;
    if (tn < 16) {
        bf16* C = (tn < 8) ? Qb : Kb;
#pragma unroll
        for (int mf = 0; mf < 4; ++mf)
#pragma unroll
            for (int j = 0; j < 4; ++j) {
                int r = tm * 256 + wm * 64 + mf * 16 + rl + j;
#pragma unroll
                for (int nf = 0; nf < 4; ++nf) {
                    int c = tnl * 128 + wn * 64 + nf * 16 + cl;
                    C[(size_t)r * ED + c] = __float2bfloat16(acc[mf][nf][j]);
                }
            }
    } else {
#pragma unroll
        for (int mf = 0; mf < 4; ++mf)
#pragma unroll
            for (int j = 0; j < 4; ++j) {
                int r = tm * 256 + wm * 64 + mf * 16 + rl + j;
                int bb = r >> 11, s = r & 2047;
#pragma unroll
                for (int nf = 0; nf < 4; ++nf) {
                    int d = tnl * 128 + wn * 64 + nf * 16 + cl;
                    Vt[(((size_t)bb << 10) + d) * SLEN + s] = __float2bfloat16(acc[mf][nf][j]);
                }
            }
    }
}

// ---------------- scores = Q @ K^T / 32, causal 256x128 tiles ---------------
// keep tile (ti,tj) iff tj <= 2*ti+1 -> 72 tiles/batch, grid (72, NB).
__global__ __launch_bounds__(512, 2) void qk_gemm(
    const bf16* __restrict__ Qb, const bf16* __restrict__ Kb, float* __restrict__ Sc)
{
    extern __shared__ char smem[];
    int bx = blockIdx.x, b = blockIdx.y, tid = threadIdx.x;
    int t = (bx & 7) * 9 + (bx >> 3);            // XCD swizzle, 72 = 8*9, bijective
    int ti = 0;
    while ((ti + 1) * (ti + 2) <= t) ++ti;       // prefix(ti) = ti*(ti+1)
    int tj = t - ti * (ti + 1);
    f32x4 acc[4][4] = {};
    gemm_core((const char*)(Qb + ((size_t)b * SLEN + ti * 256) * ED), ED * 2,
              (const char*)(Kb + ((size_t)b * SLEN + tj * 128) * ED), ED * 2,
              16, smem, tid, acc);

    float* Sb = Sc + (size_t)b * SLEN * SLEN;
    int lane = tid & 63, wave = tid >> 6, wm = wave >> 1, wn = wave & 1;
    int rl = (lane >> 4) * 4, cl = lane & 15;
#pragma unroll
    for (int mf = 0; mf < 4; ++mf)
#pragma unroll
        for (int j = 0; j < 4; ++j) {
            int r = ti * 256 + wm * 64 + mf * 16 + rl + j;
#pragma unroll
            for (int nf = 0; nf < 4; ++nf) {
                int c = tj * 128 + wn * 64 + nf * 16 + cl;
                Sb[(size_t)r * SLEN + c] = acc[mf][nf][j] * 0.03125f;
            }
        }
}

// ---------------- causal row softmax; writes P (bf16) over the score row ----
__global__ __launch_bounds__(256) void softmax_rows(float* __restrict__ Sc)
{
    int q = blockIdx.x, b = blockIdx.y, tid = threadIdx.x;
    float* row = Sc + ((size_t)b * SLEN + q) * SLEN;
    int lane = tid & 63, wave = tid >> 6;
    __shared__ float red[4];

    float vals[8];
    float lmax = -3.0e38f;
#pragma unroll
    for (int r = 0; r < 2; ++r) {
        int i4 = tid + r * 256;
        if (i4 * 4 <= q) {                       // skip fully-masked chunks
            float4 v = *(const float4*)(row + i4 * 4);
            vals[r * 4 + 0] = v.x; vals[r * 4 + 1] = v.y;
            vals[r * 4 + 2] = v.z; vals[r * 4 + 3] = v.w;
#pragma unroll
            for (int e = 0; e < 4; ++e) {
                int k = i4 * 4 + e;
                if (k <= q) lmax = fmaxf(lmax, vals[r * 4 + e]);
            }
        }
    }
#pragma unroll
    for (int o = 32; o > 0; o >>= 1) lmax = fmaxf(lmax, __shfl_xor(lmax, o));
    if (lane == 0) red[wave] = lmax;
    __syncthreads();
    float m = fmaxf(fmaxf(red[0], red[1]), fmaxf(red[2], red[3]));
    __syncthreads();
    float lsum = 0.f;
#pragma unroll
    for (int r = 0; r < 2; ++r) {
        int i4 = tid + r * 256;
        if (i4 * 4 <= q)
#pragma unroll
            for (int e = 0; e < 4; ++e) {
                int k = i4 * 4 + e;
                if (k <= q) lsum += __expf(vals[r * 4 + e] - m);
            }
    }
#pragma unroll
    for (int o = 32; o > 0; o >>= 1) lsum += __shfl_xor(lsum, o);
    if (lane == 0) red[wave] = lsum;
    __syncthreads();
    float inv = 1.0f / (red[0] + red[1] + red[2] + red[3]);
    unsigned short* prow = (unsigned short*)row;
#pragma unroll
    for (int r = 0; r < 2; ++r) {
        int i4 = tid + r * 256;
        u16x4 o4;
#pragma unroll
        for (int e = 0; e < 4; ++e) {
            int k = i4 * 4 + e;
            float p = (k <= q) ? __expf(vals[r * 4 + e] - m) * inv : 0.0f;
            o4[e] = f2bf(p);
        }
        *(u16x4*)(prow + i4 * 4) = o4;           // full store: pv reads zeros
    }
}

// ---------------- O = P @ V (P bf16 ld 4096 elems; Vt [b][d][s]) ------------
// 256x128 tiles: grid 8 mq x 8 nd x 4 b = 256 blocks (exact fill).
__global__ __launch_bounds__(512, 2) void pv_gemm(
    const bf16* __restrict__ P, const bf16* __restrict__ Vt, float* __restrict__ O)
{
    extern __shared__ char smem[];
    int mq = 7 - blockIdx.x, nd = blockIdx.y, b = blockIdx.z, tid = threadIdx.x;
    f32x4 acc[4][4] = {};
    int nkt = (mq + 1) * 4;                      // causal: k < (mq+1)*256
    gemm_core((const char*)P + ((size_t)b * SLEN + mq * 256) * 8192, 8192,
              (const char*)(Vt + ((size_t)b * ED + nd * 128) * SLEN), SLEN * 2,
              nkt, smem, tid, acc);

    int lane = tid & 63, wave = tid >> 6, wm = wave >> 1, wn = wave & 1;
    int rl = (lane >> 4) * 4, cl = lane & 15;
    float* Ob = O + (size_t)b * SLEN * ED;
#pragma unroll
    for (int mf = 0; mf < 4; ++mf)
#pragma unroll
        for (int j = 0; j < 4; ++j) {
            int r = mq * 256 + wm * 64 + mf * 16 + rl + j;
#pragma unroll
            for (int nf = 0; nf < 4; ++nf) {
                int c = nd * 128 + wn * 64 + nf * 16 + cl;
                Ob[(size_t)r * ED + c] = acc[mf][nf][j];
            }
        }
}

extern "C" void kernel_launch(void* const* d_in, const int* in_sizes, int n_in,
                              void* d_out, int out_size, void* d_ws, size_t ws_size,
                              hipStream_t stream)
{
    const float* x  = (const float*)d_in[0];
    const float* wq = (const float*)d_in[1];
    const float* wk = (const float*)d_in[2];
    const float* wv = (const float*)d_in[3];
    float* out = (float*)d_out;

    char* ws = (char*)d_ws;
    bf16* xb  = (bf16*)(ws);                       // 16 MB
    bf16* wqb = (bf16*)(ws + 16777216);            // 2 MB
    bf16* wkb = (bf16*)(ws + 18874368);            // 2 MB
    bf16* wvb = (bf16*)(ws + 20971520);            // 2 MB
    bf16* Qb  = (bf16*)(ws + 23068672);            // 16 MB
    bf16* Kb  = (bf16*)(ws + 39845888);            // 16 MB
    bf16* Vt  = (bf16*)(ws + 56623104);            // 16 MB
    float* Sc = (float*)(ws + 73400320);           // 64 MB (P bf16 aliases this)

    (void)hipFuncSetAttribute((const void*)qkv_gemm,
            hipFuncAttributeMaxDynamicSharedMemorySize, 98304);
    (void)hipFuncSetAttribute((const void*)qk_gemm,
            hipFuncAttributeMaxDynamicSharedMemorySize, 98304);
    (void)hipFuncSetAttribute((const void*)pv_gemm,
            hipFuncAttributeMaxDynamicSharedMemorySize, 98304);

    convert_to_bf16<<<5632, 256, 0, stream>>>(x, wq, wk, wv, xb, wqb, wkb, wvb);
    qkv_gemm<<<768, 512, 98304, stream>>>(xb, wqb, wkb, wvb, Qb, Kb, Vt);
    qk_gemm<<<dim3(72, NB), 512, 98304, stream>>>(Qb, Kb, Sc);
    softmax_rows<<<dim3(SLEN, NB), 256, 0, stream>>>(Sc);
    pv_gemm<<<dim3(8, 8, NB), 512, 98304, stream>>>((const bf16*)Sc, Vt, out);
}